// Round 5
// baseline (9481.895 us; speedup 1.0000x reference)
//
#include <hip/hip_runtime.h>

#define D_IN   1024
#define D_H    512
#define M_BANK 100
#define BATCH  128
#define NCOL   1224   // 100 rp | 100 wp | 512 c | 512 pre_h
#define NPAD   1280
#define KTOT   1536
#define KSH    4      // split-K partials for the fused per-step h-GEMM

typedef unsigned short u16;
typedef __attribute__((ext_vector_type(8))) short s16x8;
typedef __attribute__((ext_vector_type(4))) float f32x4;

__device__ __forceinline__ u16 f2bf(float f) {
  union { float f; unsigned int u; } v;
  v.f = f;
  unsigned int r = (v.u + 0x7FFFu + ((v.u >> 16) & 1u)) >> 16;
  return (u16)r;
}
__device__ __forceinline__ float bf2f(u16 b) {
  union { unsigned int u; float f; } v;
  v.u = ((unsigned int)b) << 16;
  return v.f;
}

// ---------------------------------------------------------------------------
// k_prep_w: W_bt[j][k] = bf16 of composite W[k][j], j in [0,1280), k in [0,1536)
//   cols [0,100)=W_rp [100,200)=W_wp [200,712)=W_c [712,1224)=Wxh/Whh else 0
// ---------------------------------------------------------------------------
__global__ void k_prep_w(const float* __restrict__ W_c,
                         const float* __restrict__ W_rp,
                         const float* __restrict__ W_wp,
                         const float* __restrict__ Wxh,
                         const float* __restrict__ Whh,
                         u16* __restrict__ W_bt) {
  const int j = blockIdx.x;
  const int k = blockIdx.y * 256 + threadIdx.x;
  float v = 0.f;
  if (j < 100)       v = W_rp[(size_t)k * M_BANK + j];
  else if (j < 200)  v = W_wp[(size_t)k * M_BANK + (j - 100)];
  else if (j < 712)  v = W_c[(size_t)k * D_H + (j - 200)];
  else if (j < NCOL) v = (k < D_IN) ? Wxh[(size_t)k * D_H + (j - 712)]
                                    : Whh[(size_t)(k - D_IN) * D_H + (j - 712)];
  W_bt[(size_t)j * KTOT + k] = f2bf(v);
}

// ---------------------------------------------------------------------------
// k_zx_mfma: hoisted x-GEMM, bf16 MFMA. zx[(b*CH+tc), j] = x @ W[0:1024, j]
// grid (NPAD/64, BATCH*CH/64), block 256 = 4 waves (2x2 of 32x32)
// ---------------------------------------------------------------------------
__global__ void k_zx_mfma(const float* __restrict__ frames,
                          const u16* __restrict__ W_bt,
                          float* __restrict__ zx,
                          int t0, int CH, int lgCH, int TF) {
  __shared__ u16 Asb[64][40];
  __shared__ u16 Bsb[64][40];
  const int tid  = threadIdx.x;
  const int lane = tid & 63;
  const int wid  = tid >> 6;
  const int wm   = wid >> 1, wn = wid & 1;
  const int j0 = blockIdx.x * 64;
  const int r0 = blockIdx.y * 64;
  const int srow = tid >> 2;
  const int skk  = (tid & 3) * 8;
  const int gr = r0 + srow;
  const int b  = gr >> lgCH;
  const int tc = gr & (CH - 1);
  const float* arow = &frames[((size_t)b * TF + t0 + tc) * D_IN];
  const u16*   brow = &W_bt[(size_t)(j0 + srow) * KTOT];

  f32x4 a00 = {0.f, 0.f, 0.f, 0.f}, a01 = {0.f, 0.f, 0.f, 0.f};
  f32x4 a10 = {0.f, 0.f, 0.f, 0.f}, a11 = {0.f, 0.f, 0.f, 0.f};

  for (int k0 = 0; k0 < D_IN; k0 += 32) {
    const float4 v0 = *reinterpret_cast<const float4*>(&arow[k0 + skk]);
    const float4 v1 = *reinterpret_cast<const float4*>(&arow[k0 + skk + 4]);
    s16x8 a8;
    a8[0] = (short)f2bf(v0.x); a8[1] = (short)f2bf(v0.y);
    a8[2] = (short)f2bf(v0.z); a8[3] = (short)f2bf(v0.w);
    a8[4] = (short)f2bf(v1.x); a8[5] = (short)f2bf(v1.y);
    a8[6] = (short)f2bf(v1.z); a8[7] = (short)f2bf(v1.w);
    *reinterpret_cast<s16x8*>(&Asb[srow][skk]) = a8;
    *reinterpret_cast<s16x8*>(&Bsb[srow][skk]) =
        *reinterpret_cast<const s16x8*>(&brow[k0 + skk]);
    __syncthreads();
    const int ka = (lane >> 4) * 8;
    const s16x8 af0 = *reinterpret_cast<s16x8*>(&Asb[wm * 32 + (lane & 15)][ka]);
    const s16x8 af1 = *reinterpret_cast<s16x8*>(&Asb[wm * 32 + 16 + (lane & 15)][ka]);
    const s16x8 bf0 = *reinterpret_cast<s16x8*>(&Bsb[wn * 32 + (lane & 15)][ka]);
    const s16x8 bf1 = *reinterpret_cast<s16x8*>(&Bsb[wn * 32 + 16 + (lane & 15)][ka]);
    a00 = __builtin_amdgcn_mfma_f32_16x16x32_bf16(af0, bf0, a00, 0, 0, 0);
    a01 = __builtin_amdgcn_mfma_f32_16x16x32_bf16(af0, bf1, a01, 0, 0, 0);
    a10 = __builtin_amdgcn_mfma_f32_16x16x32_bf16(af1, bf0, a10, 0, 0, 0);
    a11 = __builtin_amdgcn_mfma_f32_16x16x32_bf16(af1, bf1, a11, 0, 0, 0);
    __syncthreads();
  }
  const int rb = r0 + wm * 32 + (lane >> 4) * 4;
  const int cb = j0 + wn * 32 + (lane & 15);
#define STORE_ACC(A, MF, NF)                                             \
  {                                                                      \
    _Pragma("unroll")                                                    \
    for (int reg = 0; reg < 4; ++reg)                                    \
      zx[(size_t)(rb + MF * 16 + reg) * NPAD + cb + NF * 16] = A[reg];   \
  }
  STORE_ACC(a00, 0, 0) STORE_ACC(a01, 0, 1) STORE_ACC(a10, 1, 0) STORE_ACC(a11, 1, 1)
#undef STORE_ACC
}

// ---------------------------------------------------------------------------
// k_step: ONE kernel per recurrence step.
//   reads zhp_r (4 split-K partials of h_{t-1} @ W_h, from previous launch),
//   does softmaxes, c, cw=c@Wrh, M2 RMW + racc, h=relu(...), writes out,
//   then computes its OWN split-K partial of h_t @ W_h into zhp_w[p].
// grid (KSH=4, BATCH/2), block 256 = 2 batches x 4 m-groups x 32 lanes.
// block p owns h-cols [p*128,(p+1)*128) == K-slice [1024+p*128, ...) of W.
// ---------------------------------------------------------------------------
__global__ void k_step(const float* __restrict__ zx,
                       const float* __restrict__ zhp_r,
                       float* __restrict__ zhp_w,
                       const float* __restrict__ Wrh,
                       const u16* __restrict__ W_bt,
                       const float* __restrict__ b_rp,
                       const float* __restrict__ b_wp,
                       const float* __restrict__ b_c,
                       const float* __restrict__ bh,
                       float* __restrict__ M2,
                       float* __restrict__ out,
                       int t, int tc, int CH, int T, int do_next) {
  __shared__ float ar_s[2][M_BANK];
  __shared__ float aw_s[2][M_BANK];
  __shared__ float c_s[2][D_H];
  __shared__ float red[2][4][32][4];
  __shared__ float h_ls[2][128];
  const int tid  = threadIdx.x;
  const int lane = tid & 31;
  const int grp  = tid >> 5;
  const int ba   = grp >> 2;
  const int mg   = grp & 3;
  const int p    = blockIdx.x;           // col-slice & K-slice id
  const int b0   = blockIdx.y * 2;
  const int b_g  = b0 + ba;
  const int s0   = p * 128 + lane * 4;
  const bool hz  = (t > 0);
  const size_t zxrow = (size_t)(b_g * CH + tc) * NPAD;

  // ---- softmaxes (which=0 read, 1 write)
  #pragma unroll
  for (int which = 0; which < 2; ++which) {
    float lv[4];
    float mx = -1e30f;
    #pragma unroll
    for (int i = 0; i < 4; ++i) {
      const int m = lane + i * 32;
      float l = -1e30f;
      if (m < M_BANK) {
        const int col = which * 100 + m;
        l = (which ? b_wp[m] : b_rp[m]) + zx[zxrow + col];
        if (hz) {
          #pragma unroll
          for (int q = 0; q < KSH; ++q)
            l += zhp_r[(size_t)(q * BATCH + b_g) * NPAD + col];
        }
      }
      lv[i] = l;
      mx = fmaxf(mx, l);
    }
    #pragma unroll
    for (int o = 16; o; o >>= 1) mx = fmaxf(mx, __shfl_xor(mx, o, 32));
    float sum = 0.f;
    #pragma unroll
    for (int i = 0; i < 4; ++i) {
      const float e = (lane + i * 32 < M_BANK) ? __expf(lv[i] - mx) : 0.f;
      lv[i] = e;
      sum += e;
    }
    #pragma unroll
    for (int o = 16; o; o >>= 1) sum += __shfl_xor(sum, o, 32);
    const float inv = 1.0f / sum;
    #pragma unroll
    for (int i = 0; i < 4; ++i) {
      const int m = lane + i * 32;
      if (m < M_BANK) {
        if (which) aw_s[ba][m] = lv[i] * inv;
        else       ar_s[ba][m] = lv[i] * inv;
      }
    }
  }
  // ---- stage c = relu(zc + b_c) for the block's 2 batches
  for (int idx = tid; idx < 2 * D_H; idx += 256) {
    const int bb = idx >> 9;
    const int k  = idx & 511;
    const int bg2 = b0 + bb;
    float v = b_c[k] + zx[(size_t)(bg2 * CH + tc) * NPAD + 200 + k];
    if (hz) {
      #pragma unroll
      for (int q = 0; q < KSH; ++q)
        v += zhp_r[(size_t)(q * BATCH + bg2) * NPAD + 200 + k];
    }
    c_s[bb][k] = fmaxf(v, 0.f);
  }
  __syncthreads();

  // ---- cw partials over this mg's k-quarter, both batches per Wrh read
  float cwa[4] = {};
  float cwb[4] = {};
  #pragma unroll 8
  for (int kk = 0; kk < 128; ++kk) {
    const int k = mg * 128 + kk;
    const float4 w = *reinterpret_cast<const float4*>(&Wrh[k * D_H + s0]);
    const float ca = c_s[0][k];
    const float cb = c_s[1][k];
    cwa[0] += ca * w.x; cwa[1] += ca * w.y; cwa[2] += ca * w.z; cwa[3] += ca * w.w;
    cwb[0] += cb * w.x; cwb[1] += cb * w.y; cwb[2] += cb * w.z; cwb[3] += cb * w.w;
  }
  #pragma unroll
  for (int j = 0; j < 4; ++j) {
    red[0][mg][lane][j] = cwa[j];
    red[1][mg][lane][j] = cwb[j];
  }
  __syncthreads();
  float cw[4];
  #pragma unroll
  for (int j = 0; j < 4; ++j)
    cw[j] = red[ba][0][lane][j] + red[ba][1][lane][j] +
            red[ba][2][lane][j] + red[ba][3][lane][j];
  __syncthreads();

  // ---- M2 RMW (25 m-rows per thread) + racc partial
  float racc[4] = {};
  const int mbase = mg * 25;
  for (int mm = 0; mm < 25; ++mm) {
    const int m = mbase + mm;
    float* ptr = &M2[((size_t)b_g * M_BANK + m) * D_H + s0];
    const float4 v = *reinterpret_cast<const float4*>(ptr);
    const float a = ar_s[ba][m];
    const float w = aw_s[ba][m];
    racc[0] += a * v.x; racc[1] += a * v.y; racc[2] += a * v.z; racc[3] += a * v.w;
    float4 nv;
    nv.x = w * cw[0] + (1.f - w) * v.x;
    nv.y = w * cw[1] + (1.f - w) * v.y;
    nv.z = w * cw[2] + (1.f - w) * v.z;
    nv.w = w * cw[3] + (1.f - w) * v.w;
    *reinterpret_cast<float4*>(ptr) = nv;
  }
  #pragma unroll
  for (int j = 0; j < 4; ++j) red[ba][mg][lane][j] = racc[j];
  __syncthreads();

  // ---- h epilogue (mg==0 threads cover both batches x 128 cols)
  if (mg == 0) {
    float ph[4];
    const float4 vb = *reinterpret_cast<const float4*>(&bh[s0]);
    const float4 px = *reinterpret_cast<const float4*>(&zx[zxrow + 712 + s0]);
    ph[0] = vb.x + px.x; ph[1] = vb.y + px.y;
    ph[2] = vb.z + px.z; ph[3] = vb.w + px.w;
    #pragma unroll
    for (int j = 0; j < 4; ++j)
      ph[j] += red[ba][0][lane][j] + red[ba][1][lane][j] +
               red[ba][2][lane][j] + red[ba][3][lane][j];
    if (hz) {
      #pragma unroll
      for (int q = 0; q < KSH; ++q) {
        const float4 pz = *reinterpret_cast<const float4*>(
            &zhp_r[(size_t)(q * BATCH + b_g) * NPAD + 712 + s0]);
        ph[0] += pz.x; ph[1] += pz.y; ph[2] += pz.z; ph[3] += pz.w;
      }
    }
    float4 h;
    h.x = fmaxf(ph[0], 0.f); h.y = fmaxf(ph[1], 0.f);
    h.z = fmaxf(ph[2], 0.f); h.w = fmaxf(ph[3], 0.f);
    *reinterpret_cast<float4*>(&out[((size_t)b_g * T + t) * D_H + s0]) = h;
    const int sl = lane * 4;
    h_ls[ba][sl + 0] = h.x; h_ls[ba][sl + 1] = h.y;
    h_ls[ba][sl + 2] = h.z; h_ls[ba][sl + 3] = h.w;
  }
  __syncthreads();

  // ---- fused split-K partial of NEXT step's h-GEMM:
  //   zhp_w[p][b][j] = h_t[b, p*128 .. p*128+128) @ W[1024+p*128 .., j]
  if (do_next) {
    for (int jj = tid; jj < NCOL; jj += 256) {
      const u16* wr = &W_bt[(size_t)jj * KTOT + D_IN + p * 128];
      float acc0 = 0.f, acc1 = 0.f;
      #pragma unroll 4
      for (int kc = 0; kc < 128; kc += 8) {
        const s16x8 w8 = *reinterpret_cast<const s16x8*>(&wr[kc]);
        #pragma unroll
        for (int q = 0; q < 8; ++q) {
          const float wv = bf2f((u16)w8[q]);
          acc0 += h_ls[0][kc + q] * wv;
          acc1 += h_ls[1][kc + q] * wv;
        }
      }
      zhp_w[(size_t)(p * BATCH + b0 + 0) * NPAD + jj] = acc0;
      zhp_w[(size_t)(p * BATCH + b0 + 1) * NPAD + jj] = acc1;
    }
  }
}

// ---------------------------------------------------------------------------
extern "C" void kernel_launch(void* const* d_in, const int* in_sizes, int n_in,
                              void* d_out, int out_size, void* d_ws, size_t ws_size,
                              hipStream_t stream) {
  const float* frames = (const float*)d_in[0];
  const float* W_c    = (const float*)d_in[1];
  const float* b_c    = (const float*)d_in[2];
  const float* W_rp   = (const float*)d_in[3];
  const float* b_rp   = (const float*)d_in[4];
  const float* W_wp   = (const float*)d_in[5];
  const float* b_wp   = (const float*)d_in[6];
  const float* Wxh    = (const float*)d_in[7];
  const float* Wrh    = (const float*)d_in[8];
  const float* Whh    = (const float*)d_in[9];
  const float* bh     = (const float*)d_in[10];
  float* out = (float*)d_out;

  const int TF = in_sizes[0] / (BATCH * D_IN);
  const int T  = out_size / (BATCH * D_H);

  const size_t M2_ELEMS  = (size_t)BATCH * M_BANK * D_H;          // fl
  const size_t ZHP_ELEMS = (size_t)KSH * BATCH * NPAD;            // fl (x2 ping-pong)
  const size_t WBT_FL    = (size_t)NPAD * KTOT / 2;               // u16 as fl

  float* M2   = (float*)d_ws;
  float* zhp0 = M2 + M2_ELEMS;
  float* zhp1 = zhp0 + ZHP_ELEMS;
  float* zx   = zhp1 + ZHP_ELEMS;

  int CH = 32, lgCH = 5;
  while (CH > 1 &&
         ((M2_ELEMS + 2 * ZHP_ELEMS + WBT_FL +
           (size_t)BATCH * CH * NPAD) * sizeof(float) > ws_size ||
          (T % CH) != 0)) {
    CH >>= 1; --lgCH;
  }

  u16* W_bt = (u16*)(zx + (size_t)BATCH * CH * NPAD);
  float* zbuf[2] = {zhp0, zhp1};

  hipMemsetAsync(M2, 0, M2_ELEMS * sizeof(float), stream);
  k_prep_w<<<dim3(NPAD, KTOT / 256), 256, 0, stream>>>(W_c, W_rp, W_wp, Wxh, Whh, W_bt);

  for (int t0 = 0; t0 < T; t0 += CH) {
    k_zx_mfma<<<dim3(NPAD / 64, BATCH * CH / 64), 256, 0, stream>>>(
        frames, W_bt, zx, t0, CH, lgCH, TF);
    for (int t = t0; t < t0 + CH; ++t) {
      k_step<<<dim3(KSH, BATCH / 2), 256, 0, stream>>>(
          zx, zbuf[t & 1], zbuf[(t + 1) & 1], Wrh, W_bt,
          b_rp, b_wp, b_c, bh, M2, out, t, t - t0, CH, T, (t + 1 < T) ? 1 : 0);
    }
  }
}